// Round 8
// baseline (2997.671 us; speedup 1.0000x reference)
//
#include <hip/hip_runtime.h>
#include <math.h>

#define SB 32
#define SS 8192
#define SD 256
#define SH 512
#define CLIPV 3.0f

typedef __attribute__((ext_vector_type(8))) _Float16 f16x8;
typedef __attribute__((ext_vector_type(4))) float f32x4;

// fp16-pair split: x = hi + lo with residual ~2^-22 |x|  (fp16 RNE both)
__device__ __forceinline__ void split16(float v, _Float16& h, _Float16& l) {
    h = (_Float16)v;                 // RNE f32->f16
    l = (_Float16)(v - (float)h);    // v - (float)h is exact in fp32
}

// non-temporal float4 load: identical values, low cache-retention priority.
__device__ __forceinline__ float4 ntload4(const float* p) {
    f32x4 t = __builtin_nontemporal_load((const f32x4*)p);
    return make_float4(t[0], t[1], t[2], t[3]);
}

// ---------------------------------------------------------------------------
// k_prepw: split-transpose W1 (drive||resistance) into WT[col][k] fp16 hi/lo.
// (byte-identical to R5/R7 — validated)
// ---------------------------------------------------------------------------
__global__ __launch_bounds__(256) void k_prepw(
    const float* __restrict__ dw1, const float* __restrict__ rw1,
    _Float16* __restrict__ WTh, _Float16* __restrict__ WTl)
{
    const int c = blockIdx.x;
    const float* src = (c < SH) ? (dw1 + c) : (rw1 + (c - SH));
    const int k = threadIdx.x;                 // 0..255
    const float v = src[(size_t)k * SH];
    _Float16 h, l;
    split16(v, h, l);
    WTh[(size_t)c * SD + k] = h;
    WTl[(size_t)c * SD + k] = l;
}

// ---------------------------------------------------------------------------
// k_logits: fused LayerNorm + 3-term split-fp16 MFMA dual-MLP -> logits.
// ARITHMETIC BIT-IDENTICAL TO R5/R7 (twice-validated).  Scheduling changes
// only: (1) A-hi hoisted to registers (fully-unrolled k -> static indices),
// (2) hi/lo staged through ONE 32 KB LDS buffer in two rounds (lo parked in
// regs between rounds), (3) launch_bounds (256,3) for 3 waves/SIMD.
// ---------------------------------------------------------------------------
__global__ __launch_bounds__(256, 3) void k_logits(
    const float* __restrict__ x,
    const float* __restrict__ gamma, const float* __restrict__ beta,
    const _Float16* __restrict__ WTh, const _Float16* __restrict__ WTl,
    const float* __restrict__ db1, const float* __restrict__ dw2, const float* __restrict__ db2,
    const float* __restrict__ rb1, const float* __restrict__ rw2, const float* __restrict__ rb2,
    float* __restrict__ logits, float* __restrict__ murstd)
{
    __shared__ _Float16 Abuf[64 * SD];   // 32 KB; holds HI during hoist, then LO

    const int tid = threadIdx.x;
    const size_t row0 = (size_t)blockIdx.x * 64;
    char* AB = (char*)Abuf;

    // ---- stage round 1: LayerNorm; write HI to LDS, park LO in registers ----
    f16x8 Lreg[8];
    {
        const int r = (tid & 15) | ((tid >> 6) << 4);   // row 0..63
        const int q = (tid >> 4) & 3;                   // quarter of K
        const size_t row = row0 + (size_t)r;
        const float* xr = x + row * SD + q * 64;
        float4 v[16];
        float s = 0.f, sq = 0.f;
        #pragma unroll
        for (int i = 0; i < 16; ++i) {
            v[i] = ntload4(xr + i * 4);
            s  += v[i].x + v[i].y + v[i].z + v[i].w;
            sq += v[i].x*v[i].x + v[i].y*v[i].y + v[i].z*v[i].z + v[i].w*v[i].w;
        }
        s  += __shfl_xor(s, 16);  s  += __shfl_xor(s, 32);
        sq += __shfl_xor(sq, 16); sq += __shfl_xor(sq, 32);
        const float mu   = s * (1.0f / SD);
        const float var  = sq * (1.0f / SD) - mu * mu;
        const float rstd = rsqrtf(var + 1e-5f);
        if (q == 0) { murstd[2*row] = mu; murstd[2*row + 1] = rstd; }

        const float4* g4 = (const float4*)(gamma + q * 64);
        const float4* b4 = (const float4*)(beta  + q * 64);
        #pragma unroll
        for (int i = 0; i < 16; i += 2) {
            const float4 ga = g4[i], gb = g4[i+1];
            const float4 ba = b4[i], bb = b4[i+1];
            float xn[8];
            xn[0] = (v[i].x   - mu) * rstd * ga.x + ba.x;
            xn[1] = (v[i].y   - mu) * rstd * ga.y + ba.y;
            xn[2] = (v[i].z   - mu) * rstd * ga.z + ba.z;
            xn[3] = (v[i].w   - mu) * rstd * ga.w + ba.w;
            xn[4] = (v[i+1].x - mu) * rstd * gb.x + bb.x;
            xn[5] = (v[i+1].y - mu) * rstd * gb.y + bb.y;
            xn[6] = (v[i+1].z - mu) * rstd * gb.z + bb.z;
            xn[7] = (v[i+1].w - mu) * rstd * gb.w + bb.w;
            f16x8 H, L;
            #pragma unroll
            for (int j = 0; j < 8; ++j) {
                _Float16 hh, ll;
                split16(xn[j], hh, ll);
                H[j] = hh;
                L[j] = ll;
            }
            unsigned int off = (unsigned)(r * 512 + q * 128 + i * 8);
            off ^= (unsigned)((r & 7) << 4);
            *(f16x8*)(AB + off) = H;      // HI round
            Lreg[i >> 1] = L;             // LO parked in regs
        }
    }
    __syncthreads();

    // ---- hoist this wave's A-hi fragments into registers --------------------
    const int w  = tid >> 6;
    const int l  = tid & 63;
    const int lr = l & 15, lk = l >> 4;
    const unsigned int aRowByte = (unsigned)((w*16 + lr) * 512);
    const unsigned int aSwz     = (unsigned)((lr & 7) << 4);

    f16x8 AH[8];
    #pragma unroll
    for (int k = 0; k < 8; ++k)
        AH[k] = *(const f16x8*)(AB + ((aRowByte + (unsigned)(lk*16 + k*64)) ^ aSwz));
    __syncthreads();

    // ---- stage round 2: write LO halves into the same buffer ----------------
    {
        const int r = (tid & 15) | ((tid >> 6) << 4);
        const int q = (tid >> 4) & 3;
        #pragma unroll
        for (int ip = 0; ip < 8; ++ip) {
            unsigned int off = (unsigned)(r * 512 + q * 128 + ip * 16);
            off ^= (unsigned)((r & 7) << 4);
            *(f16x8*)(AB + off) = Lreg[ip];
        }
    }
    __syncthreads();

    // ---- MFMA main: wave w = rows w*16..+16; sweep 16 n-iters of 64 cols ----
    float pd[4] = {0.f,0.f,0.f,0.f};
    float pr[4] = {0.f,0.f,0.f,0.f};

    #pragma unroll 1
    for (int n = 0; n < 16; ++n) {
        const _Float16* __restrict__ bp_h = WTh + (size_t)(n * 64) * SD;
        const _Float16* __restrict__ bp_l = WTl + (size_t)(n * 64) * SD;
        f32x4 acc[4];
        #pragma unroll
        for (int ni = 0; ni < 4; ++ni) acc[ni] = (f32x4){0.f,0.f,0.f,0.f};

        #pragma unroll
        for (int k = 0; k < 8; ++k) {
            f16x8 bh[4], bl[4];
            #pragma unroll
            for (int ni = 0; ni < 4; ++ni) {
                const size_t o = (size_t)(ni*16 + lr) * SD + k*32 + lk*8;
                bh[ni] = *(const f16x8*)(bp_h + o);
                bl[ni] = *(const f16x8*)(bp_l + o);
            }
            const f16x8 al = *(const f16x8*)(AB +
                ((aRowByte + (unsigned)(lk*16 + k*64)) ^ aSwz));
            const f16x8 ah = AH[k];
            #pragma unroll
            for (int ni = 0; ni < 4; ++ni) {
                acc[ni] = __builtin_amdgcn_mfma_f32_16x16x32_f16(al, bh[ni], acc[ni], 0, 0, 0);
                acc[ni] = __builtin_amdgcn_mfma_f32_16x16x32_f16(ah, bl[ni], acc[ni], 0, 0, 0);
                acc[ni] = __builtin_amdgcn_mfma_f32_16x16x32_f16(ah, bh[ni], acc[ni], 0, 0, 0);
            }
        }
        // epilogue: bias + exact GELU + dot(w2) -> per-row partials
        const bool  isD = (n < 8);
        const float* __restrict__ B1 = isD ? db1 : rb1;
        const float* __restrict__ W2 = isD ? dw2 : rw2;
        #pragma unroll
        for (int ni = 0; ni < 4; ++ni) {
            const int col = (n & 7)*64 + ni*16 + lr;    // 0..511 within phase
            const float b1v = B1[col];
            const float w2v = W2[col];
            #pragma unroll
            for (int rg = 0; rg < 4; ++rg) {
                const float h = acc[ni][rg] + b1v;
                const float g = 0.5f * h * (1.0f + erff(h * 0.70710678118654752f));
                if (isD) pd[rg] = fmaf(g, w2v, pd[rg]);
                else     pr[rg] = fmaf(g, w2v, pr[rg]);
            }
        }
    }

    // ---- reduce across the 16 'lr' lanes (wave-local), write logits ---------
    #pragma unroll
    for (int m = 1; m <= 8; m <<= 1) {
        #pragma unroll
        for (int i = 0; i < 4; ++i) {
            pd[i] += __shfl_xor(pd[i], m);
            pr[i] += __shfl_xor(pr[i], m);
        }
    }
    if (lr == 0) {
        const float b2 = db2[0], r2 = rb2[0];
        #pragma unroll
        for (int rg = 0; rg < 4; ++rg) {
            const int row = w*16 + lk*4 + rg;
            const float D = pd[rg] + b2;
            const float R = pr[rg] + r2;
            const float sp = fmaxf(R, 0.f) + log1pf(expf(-fabsf(R)));
            float s = D - sp;
            s = fminf(CLIPV, fmaxf(-CLIPV, s));
            logits[row0 + (size_t)row] = s;
        }
    }
}

// ---------------------------------------------------------------------------
// K2: per-batch masked softmax over S + stable top-3 (validated R1/R2/R5/R7).
// ---------------------------------------------------------------------------
__global__ __launch_bounds__(256) void k_softmax_topk(
    const float* __restrict__ logits, const int* __restrict__ mask,
    float* __restrict__ weights, float* __restrict__ ti, float* __restrict__ tw,
    float* __restrict__ flags)
{
    const int b = blockIdx.x, tid = threadIdx.x;
    const float* lg = logits + (size_t)b * SS;
    const int*   mk = mask   + (size_t)b * SS;
    float*       wt = weights + (size_t)b * SS;
    __shared__ float rv[4];
    __shared__ int   ri[4];
    __shared__ int   sCh[3];

    float mx = -INFINITY;
    for (int s = tid; s < SS; s += 256) if (mk[s]) mx = fmaxf(mx, lg[s]);
    #pragma unroll
    for (int off = 32; off; off >>= 1) mx = fmaxf(mx, __shfl_xor(mx, off));
    if ((tid & 63) == 0) rv[tid >> 6] = mx;
    __syncthreads();
    mx = fmaxf(fmaxf(rv[0], rv[1]), fmaxf(rv[2], rv[3]));
    __syncthreads();

    float sm = 0.f;
    for (int s = tid; s < SS; s += 256) if (mk[s]) sm += expf(lg[s] - mx);
    #pragma unroll
    for (int off = 32; off; off >>= 1) sm += __shfl_xor(sm, off);
    if ((tid & 63) == 0) rv[tid >> 6] = sm;
    __syncthreads();
    const float Z = rv[0] + rv[1] + rv[2] + rv[3];
    __syncthreads();
    const bool  any = (Z > 0.f) && (mx > -INFINITY);
    const float inv = any ? 1.0f / Z : 0.f;

    for (int s = tid; s < SS; s += 256) {
        const float w = (mk[s] && any) ? expf(lg[s] - mx) * inv : 0.f;
        wt[s] = w;
    }
    if (tid == 0) flags[b] = any ? 1.f : 0.f;
    __syncthreads();

    for (int t = 0; t < 3; ++t) {
        float bv = -1.f; int bi = 0;
        for (int s = tid; s < SS; s += 256) {
            bool ex = false;
            for (int u = 0; u < t; ++u) ex = ex || (s == sCh[u]);
            if (ex) continue;
            const float w = wt[s];
            if (w > bv || (w == bv && s < bi)) { bv = w; bi = s; }
        }
        #pragma unroll
        for (int off = 32; off; off >>= 1) {
            const float ov = __shfl_xor(bv, off);
            const int   oi = __shfl_xor(bi, off);
            if (ov > bv || (ov == bv && oi < bi)) { bv = ov; bi = oi; }
        }
        if ((tid & 63) == 0) { rv[tid >> 6] = bv; ri[tid >> 6] = bi; }
        __syncthreads();
        if (tid == 0) {
            for (int w2 = 1; w2 < 4; ++w2)
                if (rv[w2] > rv[0] || (rv[w2] == rv[0] && ri[w2] < ri[0])) { rv[0] = rv[w2]; ri[0] = ri[w2]; }
            sCh[t] = ri[0];
            ti[b*3 + t] = (float)ri[0];
            tw[b*3 + t] = rv[0];
        }
        __syncthreads();
    }
}

// ---------------------------------------------------------------------------
// K3: partial weighted sums over S-chunks (validated R5/R7).
// ---------------------------------------------------------------------------
__global__ __launch_bounds__(256) void k_wsum(
    const float* __restrict__ x, const float* __restrict__ weights,
    const float* __restrict__ murstd,
    const float* __restrict__ gamma, const float* __restrict__ beta,
    float* __restrict__ partials)
{
    const int c = blockIdx.x;
    const int b = blockIdx.y;
    const int d = threadIdx.x;
    const float gg = gamma[d], bb = beta[d];
    float acc = 0.f;
    const size_t base = (size_t)b * SS + (size_t)c * 128;
    for (int s = 0; s < 128; ++s) {
        const size_t row = base + s;
        const float w = weights[row];
        if (w != 0.f) {
            const float mu = murstd[2*row], rs = murstd[2*row+1];
            const float xv = __builtin_nontemporal_load(&x[row * SD + d]);
            acc = fmaf(w, (xv - mu) * rs * gg + bb, acc);
        }
    }
    partials[((size_t)b * 64 + c) * SD + d] = acc;
}

// ---------------------------------------------------------------------------
// K4: reduce partials, rep[b] = svec @ vw + vb * anyMask (validated R5/R7).
// ---------------------------------------------------------------------------
__global__ __launch_bounds__(256) void k_final(
    const float* __restrict__ partials, const float* __restrict__ flags,
    const float* __restrict__ vw, const float* __restrict__ vb,
    float* __restrict__ rep)
{
    const int b = blockIdx.x;
    const int t = threadIdx.x;
    __shared__ float sv[SD];
    float a = 0.f;
    for (int c = 0; c < 64; ++c) a += partials[((size_t)b * 64 + c) * SD + t];
    sv[t] = a;
    __syncthreads();
    const float f = flags[b];
    float r = vb[t] * f;
    for (int dd = 0; dd < SD; ++dd) r = fmaf(sv[dd], vw[(size_t)dd * 256 + t], r);
    rep[(size_t)b * 256 + t] = r;
}

// ---------------------------------------------------------------------------
extern "C" void kernel_launch(void* const* d_in, const int* in_sizes, int n_in,
                              void* d_out, int out_size, void* d_ws, size_t ws_size,
                              hipStream_t stream)
{
    const float* x     = (const float*)d_in[0];
    const int*   mask  = (const int*)  d_in[1];
    const float* gamma = (const float*)d_in[2];
    const float* beta  = (const float*)d_in[3];
    const float* dw1   = (const float*)d_in[4];
    const float* db1   = (const float*)d_in[5];
    const float* dw2   = (const float*)d_in[6];
    const float* db2   = (const float*)d_in[7];
    const float* rw1   = (const float*)d_in[8];
    const float* rb1   = (const float*)d_in[9];
    const float* rw2   = (const float*)d_in[10];
    const float* rb2   = (const float*)d_in[11];
    const float* vw    = (const float*)d_in[12];
    const float* vb    = (const float*)d_in[13];

    float* out     = (float*)d_out;
    float* rep     = out;                       // 32*256
    float* weights = out + 8192;                // 32*8192
    float* ti      = out + 8192 + 262144;       // 32*3
    float* tw      = ti + 96;                   // 32*3
    float* logits  = tw + 96;                   // 32*8192

    float* ws       = (float*)d_ws;
    float* murstd   = ws;                       // 524288 floats (2 MB)
    float* partials = ws + 524288;              // 524288 floats (2 MB)
    float* flags    = ws + 1048576;             // 32 floats (+pad)
    _Float16* WTh   = (_Float16*)(ws + 1048608);          // 512 KB
    _Float16* WTl   = WTh + 262144;                        // 512 KB

    hipLaunchKernelGGL(k_prepw, dim3(1024), dim3(256), 0, stream,
                       dw1, rw1, WTh, WTl);
    hipLaunchKernelGGL(k_logits, dim3(4096), dim3(256), 0, stream,
                       x, gamma, beta, WTh, WTl,
                       db1, dw2, db2, rb1, rw2, rb2,
                       logits, murstd);
    hipLaunchKernelGGL(k_softmax_topk, dim3(32), dim3(256), 0, stream,
                       logits, mask, weights, ti, tw, flags);
    hipLaunchKernelGGL(k_wsum, dim3(64, 32), dim3(256), 0, stream,
                       x, weights, murstd, gamma, beta, partials);
    hipLaunchKernelGGL(k_final, dim3(32), dim3(256), 0, stream,
                       partials, flags, vw, vb, rep);
}

// Round 10
// 1655.884 us; speedup vs baseline: 1.8103x; 1.8103x over previous
//
#include <hip/hip_runtime.h>
#include <math.h>

#define SB 32
#define SS 8192
#define SD 256
#define SH 512
#define CLIPV 3.0f

typedef __attribute__((ext_vector_type(8))) _Float16 f16x8;
typedef __attribute__((ext_vector_type(4))) float f32x4;

// fp16-pair split: x = hi + lo with residual ~2^-22 |x|  (fp16 RNE both)
__device__ __forceinline__ void split16(float v, _Float16& h, _Float16& l) {
    h = (_Float16)v;                 // RNE f32->f16
    l = (_Float16)(v - (float)h);    // v - (float)h is exact in fp32
}

// non-temporal float4 load (validated R7: values identical, policy only)
__device__ __forceinline__ float4 ntload4(const float* p) {
    f32x4 t = __builtin_nontemporal_load((const f32x4*)p);
    return make_float4(t[0], t[1], t[2], t[3]);
}

// ---------------------------------------------------------------------------
// k_prepw: split-transpose W1 (drive||resistance) into WT[col][k] fp16 hi/lo.
// (byte-identical to R5/R7 — validated)
// ---------------------------------------------------------------------------
__global__ __launch_bounds__(256) void k_prepw(
    const float* __restrict__ dw1, const float* __restrict__ rw1,
    _Float16* __restrict__ WTh, _Float16* __restrict__ WTl)
{
    const int c = blockIdx.x;
    const float* src = (c < SH) ? (dw1 + c) : (rw1 + (c - SH));
    const int k = threadIdx.x;                 // 0..255
    const float v = src[(size_t)k * SH];
    _Float16 h, l;
    split16(v, h, l);
    WTh[(size_t)c * SD + k] = h;
    WTl[(size_t)c * SD + k] = l;
}

// ---------------------------------------------------------------------------
// k_logits: fused LayerNorm + 3-term split-fp16 MFMA dual-MLP -> logits.
// 128 rows/block in TWO sequential 64-row phases through the SAME 64 KB LDS
// (stage -> hoist to regs -> restage).  Each B fragment load now feeds two
// row-fragments: B global requests per block halved vs R7.
// PER-ROW ARITHMETIC BIT-IDENTICAL TO R5/R7 (same values, same MFMA chains,
// same epilogue and reduce order).
// ---------------------------------------------------------------------------
__global__ __launch_bounds__(256, 1) void k_logits(
    const float* __restrict__ x,
    const float* __restrict__ gamma, const float* __restrict__ beta,
    const _Float16* __restrict__ WTh, const _Float16* __restrict__ WTl,
    const float* __restrict__ db1, const float* __restrict__ dw2, const float* __restrict__ db2,
    const float* __restrict__ rb1, const float* __restrict__ rw2, const float* __restrict__ rb2,
    float* __restrict__ logits, float* __restrict__ murstd)
{
    __shared__ _Float16 Ah[64 * SD];   // 32 KB, [row][k] ^ ((row&7)<<4) byte-swizzle
    __shared__ _Float16 Al[64 * SD];   // 32 KB

    const int tid = threadIdx.x;
    const size_t row0 = (size_t)blockIdx.x * 128;
    char* AhB = (char*)Ah;
    char* AlB = (char*)Al;

    const int w  = tid >> 6;
    const int l  = tid & 63;
    const int lr = l & 15, lk = l >> 4;
    const unsigned aRowByte = (unsigned)((w*16 + lr) * 512);
    const unsigned aSwz     = (unsigned)((lr & 7) << 4);

    f16x8 AH0[8], AL0[8], AH1[8], AL1[8];

    // ---- two staging phases: rows HALF*64 .. HALF*64+63 (R7-verbatim body) --
#define STAGE_HALF(HALF, AHREG, ALREG)                                        \
    {                                                                         \
        const int r = (tid & 15) | ((tid >> 6) << 4);                         \
        const int q = (tid >> 4) & 3;                                         \
        const size_t row = row0 + (size_t)(HALF * 64 + r);                    \
        const float* xr = x + row * SD + q * 64;                              \
        float4 v[16];                                                         \
        float s = 0.f, sq = 0.f;                                              \
        _Pragma("unroll")                                                     \
        for (int i = 0; i < 16; ++i) {                                        \
            v[i] = ntload4(xr + i * 4);                                       \
            s  += v[i].x + v[i].y + v[i].z + v[i].w;                          \
            sq += v[i].x*v[i].x + v[i].y*v[i].y + v[i].z*v[i].z + v[i].w*v[i].w; \
        }                                                                     \
        s  += __shfl_xor(s, 16);  s  += __shfl_xor(s, 32);                    \
        sq += __shfl_xor(sq, 16); sq += __shfl_xor(sq, 32);                   \
        const float mu   = s * (1.0f / SD);                                   \
        const float var  = sq * (1.0f / SD) - mu * mu;                        \
        const float rstd = rsqrtf(var + 1e-5f);                               \
        if (q == 0) { murstd[2*row] = mu; murstd[2*row + 1] = rstd; }         \
        const float4* g4 = (const float4*)(gamma + q * 64);                   \
        const float4* b4 = (const float4*)(beta  + q * 64);                   \
        _Pragma("unroll")                                                     \
        for (int i = 0; i < 16; i += 2) {                                     \
            const float4 ga = g4[i], gb = g4[i+1];                            \
            const float4 ba = b4[i], bb = b4[i+1];                            \
            float xn[8];                                                      \
            xn[0] = (v[i].x   - mu) * rstd * ga.x + ba.x;                     \
            xn[1] = (v[i].y   - mu) * rstd * ga.y + ba.y;                     \
            xn[2] = (v[i].z   - mu) * rstd * ga.z + ba.z;                     \
            xn[3] = (v[i].w   - mu) * rstd * ga.w + ba.w;                     \
            xn[4] = (v[i+1].x - mu) * rstd * gb.x + bb.x;                     \
            xn[5] = (v[i+1].y - mu) * rstd * gb.y + bb.y;                     \
            xn[6] = (v[i+1].z - mu) * rstd * gb.z + bb.z;                     \
            xn[7] = (v[i+1].w - mu) * rstd * gb.w + bb.w;                     \
            f16x8 H, L;                                                       \
            _Pragma("unroll")                                                 \
            for (int j = 0; j < 8; ++j) {                                     \
                _Float16 hh, ll;                                              \
                split16(xn[j], hh, ll);                                       \
                H[j] = hh;                                                    \
                L[j] = ll;                                                    \
            }                                                                 \
            unsigned int off = (unsigned)(r * 512 + q * 128 + i * 8);         \
            off ^= (unsigned)((r & 7) << 4);                                  \
            *(f16x8*)(AhB + off) = H;                                         \
            *(f16x8*)(AlB + off) = L;                                         \
        }                                                                     \
    }                                                                         \
    __syncthreads();                                                          \
    _Pragma("unroll")                                                         \
    for (int k = 0; k < 8; ++k) {                                             \
        const unsigned off = (aRowByte + (unsigned)(lk*16 + k*64)) ^ aSwz;    \
        AHREG[k] = *(const f16x8*)(AhB + off);                                \
        ALREG[k] = *(const f16x8*)(AlB + off);                                \
    }                                                                         \
    __syncthreads();

    STAGE_HALF(0, AH0, AL0)
    STAGE_HALF(1, AH1, AL1)
#undef STAGE_HALF

    // ---- MFMA main: 16 n-iters of 64 cols; each B load feeds 2 row-frags ----
    float pd[2][4], pr[2][4];
    #pragma unroll
    for (int mi = 0; mi < 2; ++mi)
        #pragma unroll
        for (int i = 0; i < 4; ++i) { pd[mi][i] = 0.f; pr[mi][i] = 0.f; }

    #pragma unroll 1
    for (int n = 0; n < 16; ++n) {
        const _Float16* __restrict__ bp_h = WTh + (size_t)(n * 64) * SD;
        const _Float16* __restrict__ bp_l = WTl + (size_t)(n * 64) * SD;
        f32x4 acc[2][4];
        #pragma unroll
        for (int mi = 0; mi < 2; ++mi)
            #pragma unroll
            for (int ni = 0; ni < 4; ++ni) acc[mi][ni] = (f32x4){0.f,0.f,0.f,0.f};

        #pragma unroll
        for (int k = 0; k < 8; ++k) {
            f16x8 bh[4], bl[4];
            #pragma unroll
            for (int ni = 0; ni < 4; ++ni) {
                const size_t o = (size_t)(ni*16 + lr) * SD + k*32 + lk*8;
                bh[ni] = *(const f16x8*)(bp_h + o);
                bl[ni] = *(const f16x8*)(bp_l + o);
            }
            #pragma unroll
            for (int mi = 0; mi < 2; ++mi) {
                const f16x8 ah = (mi == 0) ? AH0[k] : AH1[k];
                const f16x8 al = (mi == 0) ? AL0[k] : AL1[k];
                #pragma unroll
                for (int ni = 0; ni < 4; ++ni) {
                    acc[mi][ni] = __builtin_amdgcn_mfma_f32_16x16x32_f16(al, bh[ni], acc[mi][ni], 0, 0, 0);
                    acc[mi][ni] = __builtin_amdgcn_mfma_f32_16x16x32_f16(ah, bl[ni], acc[mi][ni], 0, 0, 0);
                    acc[mi][ni] = __builtin_amdgcn_mfma_f32_16x16x32_f16(ah, bh[ni], acc[mi][ni], 0, 0, 0);
                }
            }
        }
        // epilogue: bias + exact GELU + dot(w2) -> per-row partials (R7 order)
        const bool  isD = (n < 8);
        const float* __restrict__ B1 = isD ? db1 : rb1;
        const float* __restrict__ W2 = isD ? dw2 : rw2;
        #pragma unroll
        for (int ni = 0; ni < 4; ++ni) {
            const int col = (n & 7)*64 + ni*16 + lr;    // 0..511 within phase
            const float b1v = B1[col];
            const float w2v = W2[col];
            #pragma unroll
            for (int mi = 0; mi < 2; ++mi)
                #pragma unroll
                for (int rg = 0; rg < 4; ++rg) {
                    const float h = acc[mi][ni][rg] + b1v;
                    const float g = 0.5f * h * (1.0f + erff(h * 0.70710678118654752f));
                    if (isD) pd[mi][rg] = fmaf(g, w2v, pd[mi][rg]);
                    else     pr[mi][rg] = fmaf(g, w2v, pr[mi][rg]);
                }
        }
    }

    // ---- reduce across the 16 'lr' lanes (wave-local), write logits ---------
    #pragma unroll
    for (int m = 1; m <= 8; m <<= 1) {
        #pragma unroll
        for (int mi = 0; mi < 2; ++mi)
            #pragma unroll
            for (int i = 0; i < 4; ++i) {
                pd[mi][i] += __shfl_xor(pd[mi][i], m);
                pr[mi][i] += __shfl_xor(pr[mi][i], m);
            }
    }
    if (lr == 0) {
        const float b2 = db2[0], r2 = rb2[0];
        #pragma unroll
        for (int mi = 0; mi < 2; ++mi)
            #pragma unroll
            for (int rg = 0; rg < 4; ++rg) {
                const int row = mi*64 + w*16 + lk*4 + rg;
                const float D = pd[mi][rg] + b2;
                const float R = pr[mi][rg] + r2;
                const float sp = fmaxf(R, 0.f) + log1pf(expf(-fabsf(R)));
                float s = D - sp;
                s = fminf(CLIPV, fmaxf(-CLIPV, s));
                logits[row0 + (size_t)row] = s;
            }
    }
}

// ---------------------------------------------------------------------------
// K2: per-batch masked softmax over S + stable top-3 (validated R1/R2/R5/R7).
// ---------------------------------------------------------------------------
__global__ __launch_bounds__(256) void k_softmax_topk(
    const float* __restrict__ logits, const int* __restrict__ mask,
    float* __restrict__ weights, float* __restrict__ ti, float* __restrict__ tw,
    float* __restrict__ flags)
{
    const int b = blockIdx.x, tid = threadIdx.x;
    const float* lg = logits + (size_t)b * SS;
    const int*   mk = mask   + (size_t)b * SS;
    float*       wt = weights + (size_t)b * SS;
    __shared__ float rv[4];
    __shared__ int   ri[4];
    __shared__ int   sCh[3];

    float mx = -INFINITY;
    for (int s = tid; s < SS; s += 256) if (mk[s]) mx = fmaxf(mx, lg[s]);
    #pragma unroll
    for (int off = 32; off; off >>= 1) mx = fmaxf(mx, __shfl_xor(mx, off));
    if ((tid & 63) == 0) rv[tid >> 6] = mx;
    __syncthreads();
    mx = fmaxf(fmaxf(rv[0], rv[1]), fmaxf(rv[2], rv[3]));
    __syncthreads();

    float sm = 0.f;
    for (int s = tid; s < SS; s += 256) if (mk[s]) sm += expf(lg[s] - mx);
    #pragma unroll
    for (int off = 32; off; off >>= 1) sm += __shfl_xor(sm, off);
    if ((tid & 63) == 0) rv[tid >> 6] = sm;
    __syncthreads();
    const float Z = rv[0] + rv[1] + rv[2] + rv[3];
    __syncthreads();
    const bool  any = (Z > 0.f) && (mx > -INFINITY);
    const float inv = any ? 1.0f / Z : 0.f;

    for (int s = tid; s < SS; s += 256) {
        const float w = (mk[s] && any) ? expf(lg[s] - mx) * inv : 0.f;
        wt[s] = w;
    }
    if (tid == 0) flags[b] = any ? 1.f : 0.f;
    __syncthreads();

    for (int t = 0; t < 3; ++t) {
        float bv = -1.f; int bi = 0;
        for (int s = tid; s < SS; s += 256) {
            bool ex = false;
            for (int u = 0; u < t; ++u) ex = ex || (s == sCh[u]);
            if (ex) continue;
            const float w = wt[s];
            if (w > bv || (w == bv && s < bi)) { bv = w; bi = s; }
        }
        #pragma unroll
        for (int off = 32; off; off >>= 1) {
            const float ov = __shfl_xor(bv, off);
            const int   oi = __shfl_xor(bi, off);
            if (ov > bv || (ov == bv && oi < bi)) { bv = ov; bi = oi; }
        }
        if ((tid & 63) == 0) { rv[tid >> 6] = bv; ri[tid >> 6] = bi; }
        __syncthreads();
        if (tid == 0) {
            for (int w2 = 1; w2 < 4; ++w2)
                if (rv[w2] > rv[0] || (rv[w2] == rv[0] && ri[w2] < ri[0])) { rv[0] = rv[w2]; ri[0] = ri[w2]; }
            sCh[t] = ri[0];
            ti[b*3 + t] = (float)ri[0];
            tw[b*3 + t] = rv[0];
        }
        __syncthreads();
    }
}

// ---------------------------------------------------------------------------
// K3: partial weighted sums over S-chunks (validated R5/R7).
// ---------------------------------------------------------------------------
__global__ __launch_bounds__(256) void k_wsum(
    const float* __restrict__ x, const float* __restrict__ weights,
    const float* __restrict__ murstd,
    const float* __restrict__ gamma, const float* __restrict__ beta,
    float* __restrict__ partials)
{
    const int c = blockIdx.x;
    const int b = blockIdx.y;
    const int d = threadIdx.x;
    const float gg = gamma[d], bb = beta[d];
    float acc = 0.f;
    const size_t base = (size_t)b * SS + (size_t)c * 128;
    for (int s = 0; s < 128; ++s) {
        const size_t row = base + s;
        const float w = weights[row];
        if (w != 0.f) {
            const float mu = murstd[2*row], rs = murstd[2*row+1];
            const float xv = __builtin_nontemporal_load(&x[row * SD + d]);
            acc = fmaf(w, (xv - mu) * rs * gg + bb, acc);
        }
    }
    partials[((size_t)b * 64 + c) * SD + d] = acc;
}

// ---------------------------------------------------------------------------
// K4: reduce partials, rep[b] = svec @ vw + vb * anyMask (validated R5/R7).
// ---------------------------------------------------------------------------
__global__ __launch_bounds__(256) void k_final(
    const float* __restrict__ partials, const float* __restrict__ flags,
    const float* __restrict__ vw, const float* __restrict__ vb,
    float* __restrict__ rep)
{
    const int b = blockIdx.x;
    const int t = threadIdx.x;
    __shared__ float sv[SD];
    float a = 0.f;
    for (int c = 0; c < 64; ++c) a += partials[((size_t)b * 64 + c) * SD + t];
    sv[t] = a;
    __syncthreads();
    const float f = flags[b];
    float r = vb[t] * f;
    for (int dd = 0; dd < SD; ++dd) r = fmaf(sv[dd], vw[(size_t)dd * 256 + t], r);
    rep[(size_t)b * 256 + t] = r;
}

// ---------------------------------------------------------------------------
extern "C" void kernel_launch(void* const* d_in, const int* in_sizes, int n_in,
                              void* d_out, int out_size, void* d_ws, size_t ws_size,
                              hipStream_t stream)
{
    const float* x     = (const float*)d_in[0];
    const int*   mask  = (const int*)  d_in[1];
    const float* gamma = (const float*)d_in[2];
    const float* beta  = (const float*)d_in[3];
    const float* dw1   = (const float*)d_in[4];
    const float* db1   = (const float*)d_in[5];
    const float* dw2   = (const float*)d_in[6];
    const float* db2   = (const float*)d_in[7];
    const float* rw1   = (const float*)d_in[8];
    const float* rb1   = (const float*)d_in[9];
    const float* rw2   = (const float*)d_in[10];
    const float* rb2   = (const float*)d_in[11];
    const float* vw    = (const float*)d_in[12];
    const float* vb    = (const float*)d_in[13];

    float* out     = (float*)d_out;
    float* rep     = out;                       // 32*256
    float* weights = out + 8192;                // 32*8192
    float* ti      = out + 8192 + 262144;       // 32*3
    float* tw      = ti + 96;                   // 32*3
    float* logits  = tw + 96;                   // 32*8192

    float* ws       = (float*)d_ws;
    float* murstd   = ws;                       // 524288 floats (2 MB)
    float* partials = ws + 524288;              // 524288 floats (2 MB)
    float* flags    = ws + 1048576;             // 32 floats (+pad)
    _Float16* WTh   = (_Float16*)(ws + 1048608);          // 512 KB
    _Float16* WTl   = WTh + 262144;                        // 512 KB

    hipLaunchKernelGGL(k_prepw, dim3(1024), dim3(256), 0, stream,
                       dw1, rw1, WTh, WTl);
    hipLaunchKernelGGL(k_logits, dim3(2048), dim3(256), 0, stream,
                       x, gamma, beta, WTh, WTl,
                       db1, dw2, db2, rb1, rw2, rb2,
                       logits, murstd);
    hipLaunchKernelGGL(k_softmax_topk, dim3(32), dim3(256), 0, stream,
                       logits, mask, weights, ti, tw, flags);
    hipLaunchKernelGGL(k_wsum, dim3(64, 32), dim3(256), 0, stream,
                       x, weights, murstd, gamma, beta, partials);
    hipLaunchKernelGGL(k_final, dim3(32), dim3(256), 0, stream,
                       partials, flags, vw, vb, rep);
}

// Round 11
// 710.340 us; speedup vs baseline: 4.2200x; 2.3311x over previous
//
#include <hip/hip_runtime.h>
#include <math.h>

#define SB 32
#define SS 8192
#define SD 256
#define SH 512
#define CLIPV 3.0f

typedef __attribute__((ext_vector_type(8))) _Float16 f16x8;
typedef __attribute__((ext_vector_type(4))) float f32x4;

typedef const __attribute__((address_space(1))) unsigned int gu32_t;
typedef __attribute__((address_space(3))) unsigned int lu32_t;

// fp16-pair split: x = hi + lo with residual ~2^-22 |x|  (fp16 RNE both)
__device__ __forceinline__ void split16(float v, _Float16& h, _Float16& l) {
    h = (_Float16)v;                 // RNE f32->f16
    l = (_Float16)(v - (float)h);    // v - (float)h is exact in fp32
}

// non-temporal float4 load (validated R7/R10: values identical, policy only)
__device__ __forceinline__ float4 ntload4(const float* p) {
    f32x4 t = __builtin_nontemporal_load((const f32x4*)p);
    return make_float4(t[0], t[1], t[2], t[3]);
}

// ---------------------------------------------------------------------------
// k_prepw: split-transpose W1 (drive||resistance) into WT[col][k] fp16 hi/lo.
// (byte-identical to R5/R7/R10 — validated)
// ---------------------------------------------------------------------------
__global__ __launch_bounds__(256) void k_prepw(
    const float* __restrict__ dw1, const float* __restrict__ rw1,
    _Float16* __restrict__ WTh, _Float16* __restrict__ WTl)
{
    const int c = blockIdx.x;
    const float* src = (c < SH) ? (dw1 + c) : (rw1 + (c - SH));
    const int k = threadIdx.x;                 // 0..255
    const float v = src[(size_t)k * SH];
    _Float16 h, l;
    split16(v, h, l);
    WTh[(size_t)c * SD + k] = h;
    WTl[(size_t)c * SD + k] = l;
}

// ---------------------------------------------------------------------------
// k_logits: fused LayerNorm + 3-term split-fp16 MFMA dual-MLP -> logits.
// 128 rows/block (R10-validated A path: stage->hoist twice through LDS).
// NEW: B streamed through LDS via global_load_lds DMA, 32-col tiles,
// double-buffered; B global traffic 8.4 GB -> 2.1 GB (once per block).
// LDS B layout XOR-swizzled via pre-swizzled per-lane GLOBAL source
// (rule #21: linear DMA dest + involution f(o)=o^(((o>>9)&7)<<4) on source,
// same f applied on the ds_read side -- mirrors the validated A swizzle).
// PER-ACC MFMA CHAINS AND EPILOGUE ORDER BIT-IDENTICAL TO R10.
// ---------------------------------------------------------------------------
__global__ __launch_bounds__(256, 2) void k_logits(
    const float* __restrict__ x,
    const float* __restrict__ gamma, const float* __restrict__ beta,
    const _Float16* __restrict__ WTh, const _Float16* __restrict__ WTl,
    const float* __restrict__ db1, const float* __restrict__ dw2, const float* __restrict__ db2,
    const float* __restrict__ rb1, const float* __restrict__ rw2, const float* __restrict__ rb2,
    float* __restrict__ logits, float* __restrict__ murstd)
{
    __shared__ __align__(16) char LDS[65536];  // A-stage (hi@0, lo@32768); then B dbuf (2x32KB)

    const int tid = threadIdx.x;
    const size_t row0 = (size_t)blockIdx.x * 128;
    char* AhB = LDS;
    char* AlB = LDS + 32768;

    const int w  = tid >> 6;
    const int l  = tid & 63;
    const int lr = l & 15, lk = l >> 4;
    const unsigned aRowByte = (unsigned)((w*16 + lr) * 512);
    const unsigned aSwz     = (unsigned)((lr & 7) << 4);

    f16x8 AH0[8], AL0[8], AH1[8], AL1[8];

    // ---- two A staging phases (R10-verbatim macro) ---------------------------
#define STAGE_HALF(HALF, AHREG, ALREG)                                        \
    {                                                                         \
        const int r = (tid & 15) | ((tid >> 6) << 4);                         \
        const int q = (tid >> 4) & 3;                                         \
        const size_t row = row0 + (size_t)(HALF * 64 + r);                    \
        const float* xr = x + row * SD + q * 64;                              \
        float4 v[16];                                                         \
        float s = 0.f, sq = 0.f;                                              \
        _Pragma("unroll")                                                     \
        for (int i = 0; i < 16; ++i) {                                        \
            v[i] = ntload4(xr + i * 4);                                       \
            s  += v[i].x + v[i].y + v[i].z + v[i].w;                          \
            sq += v[i].x*v[i].x + v[i].y*v[i].y + v[i].z*v[i].z + v[i].w*v[i].w; \
        }                                                                     \
        s  += __shfl_xor(s, 16);  s  += __shfl_xor(s, 32);                    \
        sq += __shfl_xor(sq, 16); sq += __shfl_xor(sq, 32);                   \
        const float mu   = s * (1.0f / SD);                                   \
        const float var  = sq * (1.0f / SD) - mu * mu;                        \
        const float rstd = rsqrtf(var + 1e-5f);                               \
        if (q == 0) { murstd[2*row] = mu; murstd[2*row + 1] = rstd; }         \
        const float4* g4 = (const float4*)(gamma + q * 64);                   \
        const float4* b4 = (const float4*)(beta  + q * 64);                   \
        _Pragma("unroll")                                                     \
        for (int i = 0; i < 16; i += 2) {                                     \
            const float4 ga = g4[i], gb = g4[i+1];                            \
            const float4 ba = b4[i], bb = b4[i+1];                            \
            float xn[8];                                                      \
            xn[0] = (v[i].x   - mu) * rstd * ga.x + ba.x;                     \
            xn[1] = (v[i].y   - mu) * rstd * ga.y + ba.y;                     \
            xn[2] = (v[i].z   - mu) * rstd * ga.z + ba.z;                     \
            xn[3] = (v[i].w   - mu) * rstd * ga.w + ba.w;                     \
            xn[4] = (v[i+1].x - mu) * rstd * gb.x + bb.x;                     \
            xn[5] = (v[i+1].y - mu) * rstd * gb.y + bb.y;                     \
            xn[6] = (v[i+1].z - mu) * rstd * gb.z + bb.z;                     \
            xn[7] = (v[i+1].w - mu) * rstd * gb.w + bb.w;                     \
            f16x8 H, L;                                                       \
            _Pragma("unroll")                                                 \
            for (int j = 0; j < 8; ++j) {                                     \
                _Float16 hh, ll;                                              \
                split16(xn[j], hh, ll);                                       \
                H[j] = hh;                                                    \
                L[j] = ll;                                                    \
            }                                                                 \
            unsigned int off = (unsigned)(r * 512 + q * 128 + i * 8);         \
            off ^= (unsigned)((r & 7) << 4);                                  \
            *(f16x8*)(AhB + off) = H;                                         \
            *(f16x8*)(AlB + off) = L;                                         \
        }                                                                     \
    }                                                                         \
    __syncthreads();                                                          \
    _Pragma("unroll")                                                         \
    for (int k = 0; k < 8; ++k) {                                             \
        const unsigned off = (aRowByte + (unsigned)(lk*16 + k*64)) ^ aSwz;    \
        AHREG[k] = *(const f16x8*)(AhB + off);                                \
        ALREG[k] = *(const f16x8*)(AlB + off);                                \
    }                                                                         \
    __syncthreads();

    STAGE_HALF(0, AH0, AL0)
    STAGE_HALF(1, AH1, AL1)
#undef STAGE_HALF

    // ---- B tile DMA staging (32 cols = 16KB hi + 16KB lo per tile) ----------
    // waves 0-1 stage hi, waves 2-3 stage lo; 8 x 1KB chunks per wave.
    const int  sIsLo  = w >> 1;                    // wave-uniform
    const int  sCc0   = (w & 1) * 8;               // wave-uniform
#define STAGE_B(T, D)                                                         \
    {                                                                         \
        const char* gsrc0 = (sIsLo ? (const char*)WTl : (const char*)WTh)     \
                            + (size_t)(T) * 16384;                            \
        char* lbase = LDS + (D) * 32768 + sIsLo * 16384;                      \
        _Pragma("unroll")                                                     \
        for (int c8 = 0; c8 < 8; ++c8) {                                      \
            const int cc = sCc0 + c8;                                         \
            const unsigned o    = (unsigned)(cc * 1024 + l * 16);             \
            const unsigned osrc = o ^ ((((o >> 9) & 7u)) << 4);               \
            __builtin_amdgcn_global_load_lds(                                 \
                (gu32_t*)(gsrc0 + osrc),                                      \
                (lu32_t*)(lbase + o), 16, 0, 0);                              \
        }                                                                     \
    }

    STAGE_B(0, 0)
    __syncthreads();   // tile 0 landed (drains vmcnt)

    // ---- MFMA main: 32 n-iters of 32 cols from LDS dbuf ---------------------
    float pd[2][4], pr[2][4];
    #pragma unroll
    for (int mi = 0; mi < 2; ++mi)
        #pragma unroll
        for (int i = 0; i < 4; ++i) { pd[mi][i] = 0.f; pr[mi][i] = 0.f; }

    #pragma unroll 1
    for (int n = 0; n < 32; ++n) {
        if (n < 31) STAGE_B(n + 1, (n + 1) & 1)

        const char* dB = LDS + (n & 1) * 32768;
        f32x4 acc[2][2];
        #pragma unroll
        for (int mi = 0; mi < 2; ++mi)
            #pragma unroll
            for (int ni = 0; ni < 2; ++ni) acc[mi][ni] = (f32x4){0.f,0.f,0.f,0.f};

        #pragma unroll
        for (int k = 0; k < 8; ++k) {
            f16x8 bh[2], bl[2];
            #pragma unroll
            for (int ni = 0; ni < 2; ++ni) {
                const unsigned u  = (unsigned)((ni*16 + lr) * 512 + k*64 + lk*16);
                const unsigned ra = u ^ aSwz;
                bh[ni] = *(const f16x8*)(dB + ra);
                bl[ni] = *(const f16x8*)(dB + 16384 + ra);
            }
            #pragma unroll
            for (int mi = 0; mi < 2; ++mi) {
                const f16x8 ah = (mi == 0) ? AH0[k] : AH1[k];
                const f16x8 al = (mi == 0) ? AL0[k] : AL1[k];
                #pragma unroll
                for (int ni = 0; ni < 2; ++ni) {
                    acc[mi][ni] = __builtin_amdgcn_mfma_f32_16x16x32_f16(al, bh[ni], acc[mi][ni], 0, 0, 0);
                    acc[mi][ni] = __builtin_amdgcn_mfma_f32_16x16x32_f16(ah, bl[ni], acc[mi][ni], 0, 0, 0);
                    acc[mi][ni] = __builtin_amdgcn_mfma_f32_16x16x32_f16(ah, bh[ni], acc[mi][ni], 0, 0, 0);
                }
            }
        }
        // epilogue: same global column order as R10 -> bit-identical partials
        const bool  isD = (n < 16);
        const float* __restrict__ B1 = isD ? db1 : rb1;
        const float* __restrict__ W2 = isD ? dw2 : rw2;
        #pragma unroll
        for (int ni = 0; ni < 2; ++ni) {
            const int col = (n & 15)*32 + ni*16 + lr;   // 0..511 within phase
            const float b1v = B1[col];
            const float w2v = W2[col];
            #pragma unroll
            for (int mi = 0; mi < 2; ++mi)
                #pragma unroll
                for (int rg = 0; rg < 4; ++rg) {
                    const float h = acc[mi][ni][rg] + b1v;
                    const float g = 0.5f * h * (1.0f + erff(h * 0.70710678118654752f));
                    if (isD) pd[mi][rg] = fmaf(g, w2v, pd[mi][rg]);
                    else     pr[mi][rg] = fmaf(g, w2v, pr[mi][rg]);
                }
        }
        __syncthreads();   // tile n reads done + tile n+1 DMA landed
    }
#undef STAGE_B

    // ---- reduce across the 16 'lr' lanes (wave-local), write logits ---------
    #pragma unroll
    for (int m = 1; m <= 8; m <<= 1) {
        #pragma unroll
        for (int mi = 0; mi < 2; ++mi)
            #pragma unroll
            for (int i = 0; i < 4; ++i) {
                pd[mi][i] += __shfl_xor(pd[mi][i], m);
                pr[mi][i] += __shfl_xor(pr[mi][i], m);
            }
    }
    if (lr == 0) {
        const float b2 = db2[0], r2 = rb2[0];
        #pragma unroll
        for (int mi = 0; mi < 2; ++mi)
            #pragma unroll
            for (int rg = 0; rg < 4; ++rg) {
                const int row = mi*64 + w*16 + lk*4 + rg;
                const float D = pd[mi][rg] + b2;
                const float R = pr[mi][rg] + r2;
                const float sp = fmaxf(R, 0.f) + log1pf(expf(-fabsf(R)));
                float s = D - sp;
                s = fminf(CLIPV, fmaxf(-CLIPV, s));
                logits[row0 + (size_t)row] = s;
            }
    }
}

// ---------------------------------------------------------------------------
// K2: per-batch masked softmax over S + stable top-3 (validated R1..R10).
// ---------------------------------------------------------------------------
__global__ __launch_bounds__(256) void k_softmax_topk(
    const float* __restrict__ logits, const int* __restrict__ mask,
    float* __restrict__ weights, float* __restrict__ ti, float* __restrict__ tw,
    float* __restrict__ flags)
{
    const int b = blockIdx.x, tid = threadIdx.x;
    const float* lg = logits + (size_t)b * SS;
    const int*   mk = mask   + (size_t)b * SS;
    float*       wt = weights + (size_t)b * SS;
    __shared__ float rv[4];
    __shared__ int   ri[4];
    __shared__ int   sCh[3];

    float mx = -INFINITY;
    for (int s = tid; s < SS; s += 256) if (mk[s]) mx = fmaxf(mx, lg[s]);
    #pragma unroll
    for (int off = 32; off; off >>= 1) mx = fmaxf(mx, __shfl_xor(mx, off));
    if ((tid & 63) == 0) rv[tid >> 6] = mx;
    __syncthreads();
    mx = fmaxf(fmaxf(rv[0], rv[1]), fmaxf(rv[2], rv[3]));
    __syncthreads();

    float sm = 0.f;
    for (int s = tid; s < SS; s += 256) if (mk[s]) sm += expf(lg[s] - mx);
    #pragma unroll
    for (int off = 32; off; off >>= 1) sm += __shfl_xor(sm, off);
    if ((tid & 63) == 0) rv[tid >> 6] = sm;
    __syncthreads();
    const float Z = rv[0] + rv[1] + rv[2] + rv[3];
    __syncthreads();
    const bool  any = (Z > 0.f) && (mx > -INFINITY);
    const float inv = any ? 1.0f / Z : 0.f;

    for (int s = tid; s < SS; s += 256) {
        const float w = (mk[s] && any) ? expf(lg[s] - mx) * inv : 0.f;
        wt[s] = w;
    }
    if (tid == 0) flags[b] = any ? 1.f : 0.f;
    __syncthreads();

    for (int t = 0; t < 3; ++t) {
        float bv = -1.f; int bi = 0;
        for (int s = tid; s < SS; s += 256) {
            bool ex = false;
            for (int u = 0; u < t; ++u) ex = ex || (s == sCh[u]);
            if (ex) continue;
            const float w = wt[s];
            if (w > bv || (w == bv && s < bi)) { bv = w; bi = s; }
        }
        #pragma unroll
        for (int off = 32; off; off >>= 1) {
            const float ov = __shfl_xor(bv, off);
            const int   oi = __shfl_xor(bi, off);
            if (ov > bv || (ov == bv && oi < bi)) { bv = ov; bi = oi; }
        }
        if ((tid & 63) == 0) { rv[tid >> 6] = bv; ri[tid >> 6] = bi; }
        __syncthreads();
        if (tid == 0) {
            for (int w2 = 1; w2 < 4; ++w2)
                if (rv[w2] > rv[0] || (rv[w2] == rv[0] && ri[w2] < ri[0])) { rv[0] = rv[w2]; ri[0] = ri[w2]; }
            sCh[t] = ri[0];
            ti[b*3 + t] = (float)ri[0];
            tw[b*3 + t] = rv[0];
        }
        __syncthreads();
    }
}

// ---------------------------------------------------------------------------
// K3: partial weighted sums over S-chunks (validated R5..R10).
// ---------------------------------------------------------------------------
__global__ __launch_bounds__(256) void k_wsum(
    const float* __restrict__ x, const float* __restrict__ weights,
    const float* __restrict__ murstd,
    const float* __restrict__ gamma, const float* __restrict__ beta,
    float* __restrict__ partials)
{
    const int c = blockIdx.x;
    const int b = blockIdx.y;
    const int d = threadIdx.x;
    const float gg = gamma[d], bb = beta[d];
    float acc = 0.f;
    const size_t base = (size_t)b * SS + (size_t)c * 128;
    for (int s = 0; s < 128; ++s) {
        const size_t row = base + s;
        const float w = weights[row];
        if (w != 0.f) {
            const float mu = murstd[2*row], rs = murstd[2*row+1];
            const float xv = __builtin_nontemporal_load(&x[row * SD + d]);
            acc = fmaf(w, (xv - mu) * rs * gg + bb, acc);
        }
    }
    partials[((size_t)b * 64 + c) * SD + d] = acc;
}

// ---------------------------------------------------------------------------
// K4: reduce partials, rep[b] = svec @ vw + vb * anyMask (validated R5..R10).
// ---------------------------------------------------------------------------
__global__ __launch_bounds__(256) void k_final(
    const float* __restrict__ partials, const float* __restrict__ flags,
    const float* __restrict__ vw, const float* __restrict__ vb,
    float* __restrict__ rep)
{
    const int b = blockIdx.x;
    const int t = threadIdx.x;
    __shared__ float sv[SD];
    float a = 0.f;
    for (int c = 0; c < 64; ++c) a += partials[((size_t)b * 64 + c) * SD + t];
    sv[t] = a;
    __syncthreads();
    const float f = flags[b];
    float r = vb[t] * f;
    for (int dd = 0; dd < SD; ++dd) r = fmaf(sv[dd], vw[(size_t)dd * 256 + t], r);
    rep[(size_t)b * 256 + t] = r;
}

// ---------------------------------------------------------------------------
extern "C" void kernel_launch(void* const* d_in, const int* in_sizes, int n_in,
                              void* d_out, int out_size, void* d_ws, size_t ws_size,
                              hipStream_t stream)
{
    const float* x     = (const float*)d_in[0];
    const int*   mask  = (const int*)  d_in[1];
    const float* gamma = (const float*)d_in[2];
    const float* beta  = (const float*)d_in[3];
    const float* dw1   = (const float*)d_in[4];
    const float* db1   = (const float*)d_in[5];
    const float* dw2   = (const float*)d_in[6];
    const float* db2   = (const float*)d_in[7];
    const float* rw1   = (const float*)d_in[8];
    const float* rb1   = (const float*)d_in[9];
    const float* rw2   = (const float*)d_in[10];
    const float* rb2   = (const float*)d_in[11];
    const float* vw    = (const float*)d_in[12];
    const float* vb    = (const float*)d_in[13];

    float* out     = (float*)d_out;
    float* rep     = out;                       // 32*256
    float* weights = out + 8192;                // 32*8192
    float* ti      = out + 8192 + 262144;       // 32*3
    float* tw      = ti + 96;                   // 32*3
    float* logits  = tw + 96;                   // 32*8192

    float* ws       = (float*)d_ws;
    float* murstd   = ws;                       // 524288 floats (2 MB)
    float* partials = ws + 524288;              // 524288 floats (2 MB)
    float* flags    = ws + 1048576;             // 32 floats (+pad)
    _Float16* WTh   = (_Float16*)(ws + 1048608);          // 512 KB
    _Float16* WTl   = WTh + 262144;                        // 512 KB

    hipLaunchKernelGGL(k_prepw, dim3(1024), dim3(256), 0, stream,
                       dw1, rw1, WTh, WTl);
    hipLaunchKernelGGL(k_logits, dim3(2048), dim3(256), 0, stream,
                       x, gamma, beta, WTh, WTl,
                       db1, dw2, db2, rb1, rw2, rb2,
                       logits, murstd);
    hipLaunchKernelGGL(k_softmax_topk, dim3(32), dim3(256), 0, stream,
                       logits, mask, weights, ti, tw, flags);
    hipLaunchKernelGGL(k_wsum, dim3(64, 32), dim3(256), 0, stream,
                       x, weights, murstd, gamma, beta, partials);
    hipLaunchKernelGGL(k_final, dim3(32), dim3(256), 0, stream,
                       partials, flags, vw, vb, rep);
}